// Round 2
// 497.371 us; speedup vs baseline: 1.2651x; 1.2651x over previous
//
#include <hip/hip_runtime.h>

#define NN 4096
#define CC 256
#define CQ 32   // C8
#define BB 4

typedef _Float16 f16x8 __attribute__((ext_vector_type(8)));
typedef float    f32x4 __attribute__((ext_vector_type(4)));

// ---------------------------------------------------------------------------
// Kernel 1: fused QKV projection (unchanged, verified).
// qT [b][n][32] f16, kT [b][m][32] f16, v [b][c][n] f16.
// ---------------------------------------------------------------------------
__global__ __launch_bounds__(256) void qkv_proj(
    const float* __restrict__ x,
    const float* __restrict__ Wq, const float* __restrict__ bq,
    const float* __restrict__ Wk, const float* __restrict__ bk,
    const float* __restrict__ Wv, const float* __restrict__ bv,
    _Float16* __restrict__ qT, _Float16* __restrict__ kT,
    _Float16* __restrict__ vf)
{
    __shared__ float Wl[16 * 256];
    __shared__ float bl[16];
    const int t = threadIdx.x;
    const int g = blockIdx.y;            // row group 0..19 (16 rows each)
    const int b = blockIdx.z;
    const int n = blockIdx.x * 256 + t;

    const float* wsrc; const float* bsrc; int rowbase;
    if (g < 2)      { wsrc = Wq; bsrc = bq; rowbase = g * 16; }
    else if (g < 4) { wsrc = Wk; bsrc = bk; rowbase = (g - 2) * 16; }
    else            { wsrc = Wv; bsrc = bv; rowbase = (g - 4) * 16; }

    #pragma unroll
    for (int i = 0; i < 16; ++i) {
        int f = i * 256 + t;
        Wl[f] = wsrc[rowbase * 256 + f];
    }
    if (t < 16) bl[t] = bsrc[rowbase + t];
    __syncthreads();

    float acc[16];
    #pragma unroll
    for (int r = 0; r < 16; ++r) acc[r] = bl[r];

    const float* xp = x + ((size_t)b * CC) * NN + n;
    for (int c = 0; c < CC; ++c) {
        float xv = xp[(size_t)c * NN];
        #pragma unroll
        for (int r = 0; r < 16; ++r) acc[r] += Wl[r * 256 + c] * xv;
    }

    if (g < 4) {
        f16x8 h0, h1;
        #pragma unroll
        for (int r = 0; r < 8; ++r) { h0[r] = (_Float16)acc[r]; h1[r] = (_Float16)acc[8 + r]; }
        _Float16* dst = (g < 2) ? qT : kT;
        int half = (g < 2) ? g : (g - 2);
        size_t base = ((size_t)b * NN + n) * CQ + half * 16;
        *(f16x8*)&dst[base]     = h0;
        *(f16x8*)&dst[base + 8] = h1;
    } else {
        const int c0 = (g - 4) * 16;
        #pragma unroll
        for (int r = 0; r < 16; ++r)
            vf[((size_t)b * CC + c0 + r) * NN + n] = (_Float16)acc[r];
    }
}

// ---------------------------------------------------------------------------
// Kernel 2: fully fused attention.
// One block per (b, 64-row m-tile). 256 threads = 4 waves.
//  pass A: stats[m] (online max/expsum over all n), barrier-free loop.
//  pass B: recompute S tile, P = exp(S-M)*rS; write A (global f32) and
//          Pl (LDS f16); accumulate o[c][m] += v[c][n]*P[m][n] via MFMA.
//  epilogue: out = x + gamma*o.
// Frag conventions copied from the previously verified kernels:
//   af = row-frags of A-operand (rows = K-rows / V-rows), bf = rows of
//   B-operand (Q-rows / P-rows); D: row = A-op rows, col = B-op rows;
//   frag read: row base + (l&15), k-offset (l>>4)*8.
// ---------------------------------------------------------------------------
__global__ __launch_bounds__(256) void attn_fused(
    const _Float16* __restrict__ qT, const _Float16* __restrict__ kT,
    const _Float16* __restrict__ vf, const float* __restrict__ x,
    const float* __restrict__ gamma,
    float* __restrict__ A, float* __restrict__ out)
{
    __shared__ __align__(16) _Float16 Pl[64 * 136];  // [m][n], pad stride 136
    __shared__ float2 sred[4][64];
    __shared__ float2 sstat[64];

    const int t  = threadIdx.x;
    const int l  = t & 63, w = t >> 6;
    const int lr = l & 15, lg = l >> 4;
    const int m0 = blockIdx.x * 64;
    const int b  = blockIdx.y;

    // persistent K fragments for this m-tile (m rows = g*16 + lr)
    f16x8 kf[4];
    #pragma unroll
    for (int g = 0; g < 4; ++g)
        kf[g] = *(const f16x8*)&kT[((size_t)b * NN + m0 + g * 16 + lr) * CQ + lg * 8];

    const _Float16* qb = qT + (size_t)b * NN * CQ;

    // ---------------- pass A: stats ----------------
    float mx[4][4], sm[4][4];
    #pragma unroll
    for (int g = 0; g < 4; ++g)
        #pragma unroll
        for (int r = 0; r < 4; ++r) { mx[g][r] = -1e30f; sm[g][r] = 0.0f; }

    for (int nt = 0; nt < NN / 128; ++nt) {
        f16x8 qf[2];
        #pragma unroll
        for (int h = 0; h < 2; ++h)
            qf[h] = *(const f16x8*)&qb[(size_t)(nt * 128 + w * 32 + h * 16 + lr) * CQ + lg * 8];
        #pragma unroll
        for (int g = 0; g < 4; ++g) {
            f32x4 s0 = (f32x4){0.f, 0.f, 0.f, 0.f};
            f32x4 s1 = (f32x4){0.f, 0.f, 0.f, 0.f};
            s0 = __builtin_amdgcn_mfma_f32_16x16x32_f16(kf[g], qf[0], s0, 0, 0, 0);
            s1 = __builtin_amdgcn_mfma_f32_16x16x32_f16(kf[g], qf[1], s1, 0, 0, 0);
            #pragma unroll
            for (int r = 0; r < 4; ++r) {
                float t0 = fmaxf(s0[r], s1[r]);
                float nm = fmaxf(mx[g][r], t0);
                float sadd = __expf(s0[r] - nm) + __expf(s1[r] - nm);
                sm[g][r] = sm[g][r] * __expf(mx[g][r] - nm) + sadd;
                mx[g][r] = nm;
            }
        }
    }

    // reduce across the 16 lanes (l&15) sharing each m-row
    #pragma unroll
    for (int off = 1; off < 16; off <<= 1)
        #pragma unroll
        for (int g = 0; g < 4; ++g)
            #pragma unroll
            for (int r = 0; r < 4; ++r) {
                float pm = __shfl_xor(mx[g][r], off, 64);
                float ps = __shfl_xor(sm[g][r], off, 64);
                float nm = fmaxf(mx[g][r], pm);
                sm[g][r] = sm[g][r] * __expf(mx[g][r] - nm) + ps * __expf(pm - nm);
                mx[g][r] = nm;
            }

    if (lr == 0) {
        #pragma unroll
        for (int g = 0; g < 4; ++g)
            #pragma unroll
            for (int r = 0; r < 4; ++r)
                sred[w][g * 16 + lg * 4 + r] = make_float2(mx[g][r], sm[g][r]);
    }
    __syncthreads();
    if (t < 64) {
        float2 a0 = sred[0][t], a1 = sred[1][t], a2 = sred[2][t], a3 = sred[3][t];
        float M = fmaxf(fmaxf(a0.x, a1.x), fmaxf(a2.x, a3.x));
        float S = a0.y * __expf(a0.x - M) + a1.y * __expf(a1.x - M)
                + a2.y * __expf(a2.x - M) + a3.y * __expf(a3.x - M);
        sstat[t] = make_float2(M, 1.0f / S);
    }
    __syncthreads();

    float2 stt[4][4];
    #pragma unroll
    for (int g = 0; g < 4; ++g)
        #pragma unroll
        for (int r = 0; r < 4; ++r)
            stt[g][r] = sstat[g * 16 + lg * 4 + r];

    // ---------------- pass B: write A + accumulate o ----------------
    f32x4 acc[4][4];   // o rows c = w*64 + g*16 + lg*4 + r ; cols m = h*16 + lr
    #pragma unroll
    for (int g = 0; g < 4; ++g)
        #pragma unroll
        for (int h = 0; h < 4; ++h)
            acc[g][h] = (f32x4){0.f, 0.f, 0.f, 0.f};

    const _Float16* vb = vf + ((size_t)b * CC + w * 64) * NN;
    float* Ab = A + ((size_t)b * NN + m0) * NN;

    for (int nt = 0; nt < NN / 128; ++nt) {
        // S strip for this wave: m 0..63, n = w*32 + h*16 + lr
        f16x8 qf[2];
        #pragma unroll
        for (int h = 0; h < 2; ++h)
            qf[h] = *(const f16x8*)&qb[(size_t)(nt * 128 + w * 32 + h * 16 + lr) * CQ + lg * 8];

        float p[4][2][4];
        #pragma unroll
        for (int g = 0; g < 4; ++g) {
            f32x4 s0 = (f32x4){0.f, 0.f, 0.f, 0.f};
            f32x4 s1 = (f32x4){0.f, 0.f, 0.f, 0.f};
            s0 = __builtin_amdgcn_mfma_f32_16x16x32_f16(kf[g], qf[0], s0, 0, 0, 0);
            s1 = __builtin_amdgcn_mfma_f32_16x16x32_f16(kf[g], qf[1], s1, 0, 0, 0);
            #pragma unroll
            for (int r = 0; r < 4; ++r) {
                p[g][0][r] = __expf(s0[r] - stt[g][r].x) * stt[g][r].y;
                p[g][1][r] = __expf(s1[r] - stt[g][r].x) * stt[g][r].y;
            }
        }

        __syncthreads();   // previous iteration's Pl reads complete

        #pragma unroll
        for (int g = 0; g < 4; ++g)
            #pragma unroll
            for (int h = 0; h < 2; ++h)
                #pragma unroll
                for (int r = 0; r < 4; ++r) {
                    int m = g * 16 + lg * 4 + r;
                    int nc = w * 32 + h * 16 + lr;
                    Pl[m * 136 + nc] = (_Float16)p[g][h][r];
                }

        __syncthreads();   // Pl visible to all waves

        // A stores issued here so they drain under the PV MFMA phase
        #pragma unroll
        for (int g = 0; g < 4; ++g)
            #pragma unroll
            for (int h = 0; h < 2; ++h)
                #pragma unroll
                for (int r = 0; r < 4; ++r) {
                    int m = g * 16 + lg * 4 + r;
                    int nc = w * 32 + h * 16 + lr;
                    Ab[(size_t)m * NN + nt * 128 + nc] = p[g][h][r];
                }

        // PV: o[c][m] += v[c][n] * P[m][n], k = n (128 per tile, 4 slices)
        #pragma unroll
        for (int ks = 0; ks < 4; ++ks) {
            f16x8 vfr[4], pfr[4];
            #pragma unroll
            for (int g = 0; g < 4; ++g)
                vfr[g] = *(const f16x8*)&vb[(size_t)(g * 16 + lr) * NN + nt * 128 + ks * 32 + lg * 8];
            #pragma unroll
            for (int h = 0; h < 4; ++h)
                pfr[h] = *(const f16x8*)&Pl[(h * 16 + lr) * 136 + ks * 32 + lg * 8];
            #pragma unroll
            for (int g = 0; g < 4; ++g)
                #pragma unroll
                for (int h = 0; h < 4; ++h)
                    acc[g][h] = __builtin_amdgcn_mfma_f32_16x16x32_f16(
                        vfr[g], pfr[h], acc[g][h], 0, 0, 0);
        }
    }

    // epilogue: out = x + gamma*o ; D row = c (A-op rows), col = m (B-op rows)
    const float gm = gamma[0];
    #pragma unroll
    for (int g = 0; g < 4; ++g) {
        #pragma unroll
        for (int r = 0; r < 4; ++r) {
            int c = w * 64 + g * 16 + lg * 4 + r;
            size_t ro = ((size_t)b * CC + c) * NN + m0;
            #pragma unroll
            for (int h = 0; h < 4; ++h) {
                int m = h * 16 + lr;
                out[ro + m] = x[ro + m] + gm * acc[g][h][r];
            }
        }
    }
}

// ---------------------------------------------------------------------------
extern "C" void kernel_launch(void* const* d_in, const int* in_sizes, int n_in,
                              void* d_out, int out_size, void* d_ws, size_t ws_size,
                              hipStream_t stream) {
    const float* x     = (const float*)d_in[0];
    const float* Wq    = (const float*)d_in[1];
    const float* bq    = (const float*)d_in[2];
    const float* Wk    = (const float*)d_in[3];
    const float* bk    = (const float*)d_in[4];
    const float* Wv    = (const float*)d_in[5];
    const float* bv    = (const float*)d_in[6];
    const float* gamma = (const float*)d_in[7];

    float* out = (float*)d_out;                       // [B, C, H, W]
    float* A   = out + (size_t)BB * CC * NN;          // [B, N, N] attention_map

    _Float16* qT = (_Float16*)d_ws;                   // [B, N, 32]
    _Float16* kT = qT + (size_t)BB * NN * CQ;         // [B, N, 32]
    _Float16* vf = kT + (size_t)BB * NN * CQ;         // [B, C, N]

    qkv_proj  <<<dim3(NN / 256, 20, BB), 256, 0, stream>>>(x, Wq, bq, Wk, bk, Wv, bv, qT, kT, vf);
    attn_fused<<<dim3(NN / 64, BB),      256, 0, stream>>>(qT, kT, vf, x, gamma, A, out);
}